// Round 1
// baseline (577.142 us; speedup 1.0000x reference)
//
#include <hip/hip_runtime.h>

#define LQ     22500
#define SPA_H  58
#define SPA_W  100
#define S_TOT  5800
#define NCAMS  6
#define CDIM   256

typedef __attribute__((ext_vector_type(8))) _Float16 half8;
typedef __attribute__((ext_vector_type(4))) float f32x4;

__device__ __forceinline__ half8 cvt_f32x8(const float* p) {
  f32x4 a = *(const f32x4*)p;
  f32x4 b = *(const f32x4*)(p + 4);
  half8 r;
  r[0] = (_Float16)a.x; r[1] = (_Float16)a.y; r[2] = (_Float16)a.z; r[3] = (_Float16)a.w;
  r[4] = (_Float16)b.x; r[5] = (_Float16)b.y; r[6] = (_Float16)b.z; r[7] = (_Float16)b.w;
  return r;
}

// One pass: convert W_val/W_out to f16, build concatenated [W_off;W_attn] f16,
// and the concatenated f32 bias for the fused query GEMM.
__global__ __launch_bounds__(256) void cvt_weights_all(
    const float* __restrict__ Wv, const float* __restrict__ Wo,
    const float* __restrict__ Wf, const float* __restrict__ Wa,
    const float* __restrict__ bf, const float* __restrict__ ba,
    _Float16* __restrict__ dst, float* __restrict__ biascat) {
  const int i = blockIdx.x * 256 + threadIdx.x;
  if (i < 192) biascat[i] = (i < 128) ? bf[i] : ba[i - 128];
  if (i >= 180224) return;
  float v;
  if (i < 65536)       v = Wv[i];
  else if (i < 131072) v = Wo[i - 65536];
  else { const int j = i - 131072; v = (j < 32768) ? Wf[j] : Wa[j - 32768]; }
  dst[i] = (_Float16)v;
}

// C[M x N] = A[M x 256] @ W[N x 256]^T + bias.  64-row M-tile, 4 waves own
// disjoint column ranges, B-fragments reused across 4 row-tiles.
// A_F16: A f16 else f32 (inline cvt). W f16. OUT_MODE: 0=f32, 2=f16.
template<int N, bool A_F16, int OUT_MODE>
__global__ __launch_bounds__(256, 2) void gemm64(
    const void* __restrict__ Av, const _Float16* __restrict__ W,
    const float* __restrict__ bias, void* __restrict__ Cv, int M) {
  constexpr int K  = CDIM;
  constexpr int NT = (N / 4) / 16;
  const int lane = threadIdx.x & 63;
  const int wave = threadIdx.x >> 6;
  const int m15  = lane & 15;
  const int quad = lane >> 4;
  const int rowbase = blockIdx.x * 64;
  const int colbase = wave * (N / 4);

  f32x4 acc[4][NT];
#pragma unroll
  for (int rt = 0; rt < 4; ++rt)
#pragma unroll
    for (int t = 0; t < NT; ++t) acc[rt][t] = (f32x4){0.f, 0.f, 0.f, 0.f};

#pragma unroll
  for (int kk = 0; kk < K; kk += 32) {
    const int ko = kk + quad * 8;
    half8 a[4], b[NT];
#pragma unroll
    for (int rt = 0; rt < 4; ++rt) {
      int row = rowbase + rt * 16 + m15;
      row = row < M ? row : M - 1;
      if (A_F16) a[rt] = *(const half8*)((const _Float16*)Av + (size_t)row * K + ko);
      else       a[rt] = cvt_f32x8((const float*)Av + (size_t)row * K + ko);
    }
#pragma unroll
    for (int t = 0; t < NT; ++t)
      b[t] = *(const half8*)(W + (size_t)(colbase + t * 16 + m15) * K + ko);
#pragma unroll
    for (int t = 0; t < NT; ++t)
#pragma unroll
      for (int rt = 0; rt < 4; ++rt)
        acc[rt][t] = __builtin_amdgcn_mfma_f32_16x16x32_f16(a[rt], b[t], acc[rt][t], 0, 0, 0);
  }

#pragma unroll
  for (int rt = 0; rt < 4; ++rt) {
    const int orow = rowbase + rt * 16 + quad * 4;
#pragma unroll
    for (int t = 0; t < NT; ++t) {
      const int col = colbase + t * 16 + m15;
      const float bv = bias[col];
#pragma unroll
      for (int i = 0; i < 4; ++i) {
        const int r = orow + i;
        if (r < M) {
          const float v = acc[rt][t][i] + bv;
          if (OUT_MODE == 0) ((float*)Cv)[(size_t)r * N + col] = v;
          else               ((_Float16*)Cv)[(size_t)r * N + col] = (_Float16)v;
        }
      }
    }
  }
}

// 8 queries/block of 128. Thread: ql=t>>4, s=t&15, head h=s>>1, 16 channels.
// Branch-free gather: all 4 taps clamped+weight-zeroed, 8 loads in flight per
// point, 8-point loop fully unrolled so loads of point p+1 hide under FMAs of p.
__global__ __launch_bounds__(128, 4) void sampler(
    const _Float16* __restrict__ vp,     // (6, 5800, 256) f16
    const _Float16* __restrict__ qproj,  // (LQ, 192) f16: [0,128)=off, [128,192)=attn
    const float* __restrict__ ref,       // f32 (6, 1, LQ, 4, 2)
    const int* __restrict__ bev,         // int32 (6, 1, LQ, 4)
    _Float16* __restrict__ slots)        // (LQ, 256) f16
{
  const int t  = threadIdx.x;
  const int ql = t >> 4;
  const int s  = t & 15;
  const int h  = s >> 1;
  const int hf = s & 1;
  const int q  = blockIdx.x * 8 + ql;
  const bool qok = q < LQ;

  __shared__ float s_off[8][128];
  __shared__ float s_aw[8][64];
  __shared__ float s_ref[8][48];
  __shared__ int   s_vis[8][6];

  if (s < 6) s_vis[ql][s] = 0;
  if (qok) {
    const _Float16* qp = qproj + (size_t)q * 192;
#pragma unroll
    for (int rep = 0; rep < 12; ++rep) {
      const int j = s + rep * 16;
      const float v = (float)qp[j];
      if (j < 128) s_off[ql][j] = v * ((j & 1) ? (1.f / 58.f) : (1.f / 100.f));
      else         s_aw[ql][j - 128] = v;
    }
#pragma unroll
    for (int rep = 0; rep < 3; ++rep) {
      const int k = s + rep * 16;
      s_ref[ql][k] = ref[((size_t)(k >> 3) * LQ + q) * 8 + (k & 7)];
    }
    if (s < 6) {
      const int* bm = bev + ((size_t)s * LQ + q) * 4;
      s_vis[ql][s] = (bm[0] + bm[1] + bm[2] + bm[3]) > 0 ? 1 : 0;
    }
  }
  __syncthreads();

  // per-head softmax (redundant across the 2 lanes of a head)
  float w8[8];
  {
    float m = -1e30f;
#pragma unroll
    for (int p = 0; p < 8; ++p) m = fmaxf(m, s_aw[ql][h * 8 + p]);
    float ssum = 0.f;
#pragma unroll
    for (int p = 0; p < 8; ++p) { w8[p] = __expf(s_aw[ql][h * 8 + p] - m); ssum += w8[p]; }
    const float inv = 1.f / ssum;
#pragma unroll
    for (int p = 0; p < 8; ++p) w8[p] *= inv;
  }

  // hoist this head's offsets out of LDS (kills per-point bank-conflicted reads)
  float ox[8], oy[8];
#pragma unroll
  for (int p = 0; p < 8; ++p) {
    ox[p] = s_off[ql][(h * 8 + p) * 2 + 0];
    oy[p] = s_off[ql][(h * 8 + p) * 2 + 1];
  }

  int cnt = 0;
#pragma unroll
  for (int c = 0; c < 6; ++c) cnt += s_vis[ql][c];
  const float invc = 1.f / (float)(cnt > 0 ? cnt : 1);

  float acc[16];
#pragma unroll
  for (int i = 0; i < 16; ++i) acc[i] = 0.f;

  const int chbase = h * 32 + hf * 16;

  for (int cam = 0; cam < NCAMS; ++cam) {
    // branch-free: invisible cam -> camw 0 -> all tap weights 0.
    // (wave-level skip probability is ~(1/16)^4 per query anyway)
    const float camw = (float)s_vis[ql][cam];
    const _Float16* vpc = vp + (size_t)cam * (S_TOT * CDIM) + chbase;
    float rx[4], ry[4];
#pragma unroll
    for (int z = 0; z < 4; ++z) {
      rx[z] = s_ref[ql][cam * 8 + z * 2 + 0];
      ry[z] = s_ref[ql][cam * 8 + z * 2 + 1];
    }
#pragma unroll
    for (int p = 0; p < 8; ++p) {
      const int z = p & 3;
      const float x = (rx[z] + ox[p]) * 100.f - 0.5f;
      const float y = (ry[z] + oy[p]) * 58.f - 0.5f;
      const float x0f = floorf(x), y0f = floorf(y);
      const float fx = x - x0f, fy = y - y0f;
      const int x0 = (int)x0f, y0 = (int)y0f;
      const int x1 = x0 + 1,  y1 = y0 + 1;
      const float wgt = w8[p] * camw;
      const float gx0 = 1.f - fx, gx1 = fx;
      const float gy0 = (1.f - fy) * wgt, gy1 = fy * wgt;
      // validity folded into weights; addresses clamped in-bounds
      const float vx0 = ((unsigned)x0 < SPA_W) ? 1.f : 0.f;
      const float vx1 = ((unsigned)x1 < SPA_W) ? 1.f : 0.f;
      const float vy0 = ((unsigned)y0 < SPA_H) ? 1.f : 0.f;
      const float vy1 = ((unsigned)y1 < SPA_H) ? 1.f : 0.f;
      const float w00 = gy0 * gx0 * (vy0 * vx0);
      const float w01 = gy0 * gx1 * (vy0 * vx1);
      const float w10 = gy1 * gx0 * (vy1 * vx0);
      const float w11 = gy1 * gx1 * (vy1 * vx1);
      const int x0c = min(max(x0, 0), SPA_W - 1);
      const int x1c = min(max(x1, 0), SPA_W - 1);
      const int y0c = min(max(y0, 0), SPA_H - 1);
      const int y1c = min(max(y1, 0), SPA_H - 1);
      const int r0 = y0c * SPA_W, r1 = y1c * SPA_W;
      const _Float16* p00 = vpc + ((size_t)(r0 + x0c) << 8);
      const _Float16* p01 = vpc + ((size_t)(r0 + x1c) << 8);
      const _Float16* p10 = vpc + ((size_t)(r1 + x0c) << 8);
      const _Float16* p11 = vpc + ((size_t)(r1 + x1c) << 8);
      // 8 loads issued back-to-back, then consumed
      half8 a00 = *(const half8*)p00;       half8 b00 = *(const half8*)(p00 + 8);
      half8 a01 = *(const half8*)p01;       half8 b01 = *(const half8*)(p01 + 8);
      half8 a10 = *(const half8*)p10;       half8 b10 = *(const half8*)(p10 + 8);
      half8 a11 = *(const half8*)p11;       half8 b11 = *(const half8*)(p11 + 8);
#pragma unroll
      for (int i = 0; i < 8; ++i) {
        float v = acc[i];
        v = fmaf(w00, (float)a00[i], v);
        v = fmaf(w01, (float)a01[i], v);
        v = fmaf(w10, (float)a10[i], v);
        v = fmaf(w11, (float)a11[i], v);
        acc[i] = v;
        float u = acc[8 + i];
        u = fmaf(w00, (float)b00[i], u);
        u = fmaf(w01, (float)b01[i], u);
        u = fmaf(w10, (float)b10[i], u);
        u = fmaf(w11, (float)b11[i], u);
        acc[8 + i] = u;
      }
    }
  }

  if (qok) {
    half8 o0, o1;
#pragma unroll
    for (int i = 0; i < 8; ++i) { o0[i] = (_Float16)(acc[i] * invc); o1[i] = (_Float16)(acc[8 + i] * invc); }
    _Float16* sp = slots + (size_t)q * CDIM + chbase;
    *(half8*)sp = o0;
    *(half8*)(sp + 8) = o1;
  }
}

extern "C" void kernel_launch(void* const* d_in, const int* in_sizes, int n_in,
                              void* d_out, int out_size, void* d_ws, size_t ws_size,
                              hipStream_t stream) {
  const float* query  = (const float*)d_in[0];
  const float* refpts = (const float*)d_in[1];
  const int*   bev    = (const int*)d_in[2];
  const float* value  = (const float*)d_in[3];
  const float* W_off  = (const float*)d_in[4];
  const float* b_off  = (const float*)d_in[5];
  const float* W_attn = (const float*)d_in[6];
  const float* b_attn = (const float*)d_in[7];
  const float* W_val  = (const float*)d_in[8];
  const float* b_val  = (const float*)d_in[9];
  const float* W_out  = (const float*)d_in[10];
  const float* b_out  = (const float*)d_in[11];

  char* ws = (char*)d_ws;
  _Float16* Wv_h    = (_Float16*)(ws + 0);        // 65536 f16
  _Float16* Wo_h    = (_Float16*)(ws + 131072);   // 65536 f16
  _Float16* Wcat_h  = (_Float16*)(ws + 262144);   // 49152 f16 (end 360448)
  float*    biascat = (float*)   (ws + 360448);   // 192 f32 (end 361216)
  _Float16* vp      = (_Float16*)(ws + 361216);   // 34800*256 f16 = 17,817,600
  _Float16* qproj   = (_Float16*)(ws + 18178816); // 22500*192 f16 =  8,640,000
  _Float16* slots   = (_Float16*)(ws + 26818816); // 22500*256 f16 = 11,520,000
                                                  // total: 38,338,816 B

  cvt_weights_all<<<704, 256, 0, stream>>>(W_val, W_out, W_off, W_attn,
                                           b_off, b_attn, Wv_h, biascat);

  // value projection: 34800 x 256
  gemm64<256, false, 2><<<(34800 + 63) / 64, 256, 0, stream>>>(value, Wv_h, b_val, vp, 34800);
  // fused query projection: 22500 x 192 (off ++ attn)
  gemm64<192, false, 2><<<(LQ + 63) / 64, 256, 0, stream>>>(query, Wcat_h, biascat, qproj, LQ);

  sampler<<<(LQ + 7) / 8, 128, 0, stream>>>(vp, qproj, refpts, bev, slots);

  // output projection: f16 slots -> f32 d_out
  gemm64<256, true, 0><<<(LQ + 63) / 64, 256, 0, stream>>>(slots, Wo_h, b_out, d_out, LQ);
}

// Round 2
// 476.683 us; speedup vs baseline: 1.2107x; 1.2107x over previous
//
#include <hip/hip_runtime.h>

#define LQ     22500
#define SPA_H  58
#define SPA_W  100
#define S_TOT  5800
#define NCAMS  6
#define CDIM   256

typedef __attribute__((ext_vector_type(8))) _Float16 half8;
typedef __attribute__((ext_vector_type(4))) float f32x4;

__device__ __forceinline__ half8 cvt_f32x8(const float* p) {
  f32x4 a = *(const f32x4*)p;
  f32x4 b = *(const f32x4*)(p + 4);
  half8 r;
  r[0] = (_Float16)a.x; r[1] = (_Float16)a.y; r[2] = (_Float16)a.z; r[3] = (_Float16)a.w;
  r[4] = (_Float16)b.x; r[5] = (_Float16)b.y; r[6] = (_Float16)b.z; r[7] = (_Float16)b.w;
  return r;
}

// One pass: convert W_val/W_out to f16, build concatenated [W_off;W_attn] f16,
// and the concatenated f32 bias for the fused query GEMM.
__global__ __launch_bounds__(256) void cvt_weights_all(
    const float* __restrict__ Wv, const float* __restrict__ Wo,
    const float* __restrict__ Wf, const float* __restrict__ Wa,
    const float* __restrict__ bf, const float* __restrict__ ba,
    _Float16* __restrict__ dst, float* __restrict__ biascat) {
  const int i = blockIdx.x * 256 + threadIdx.x;
  if (i < 192) biascat[i] = (i < 128) ? bf[i] : ba[i - 128];
  if (i >= 180224) return;
  float v;
  if (i < 65536)       v = Wv[i];
  else if (i < 131072) v = Wo[i - 65536];
  else { const int j = i - 131072; v = (j < 32768) ? Wf[j] : Wa[j - 32768]; }
  dst[i] = (_Float16)v;
}

// C[M x N] = A[M x 256] @ W[N x 256]^T + bias.  64-row M-tile, 4 waves own
// disjoint column ranges, B-fragments reused across 4 row-tiles.
// A_F16: A f16 else f32 (inline cvt). W f16. OUT_MODE: 0=f32, 2=f16.
template<int N, bool A_F16, int OUT_MODE>
__global__ __launch_bounds__(256, 2) void gemm64(
    const void* __restrict__ Av, const _Float16* __restrict__ W,
    const float* __restrict__ bias, void* __restrict__ Cv, int M) {
  constexpr int K  = CDIM;
  constexpr int NT = (N / 4) / 16;
  const int lane = threadIdx.x & 63;
  const int wave = threadIdx.x >> 6;
  const int m15  = lane & 15;
  const int quad = lane >> 4;
  const int rowbase = blockIdx.x * 64;
  const int colbase = wave * (N / 4);

  f32x4 acc[4][NT];
#pragma unroll
  for (int rt = 0; rt < 4; ++rt)
#pragma unroll
    for (int t = 0; t < NT; ++t) acc[rt][t] = (f32x4){0.f, 0.f, 0.f, 0.f};

#pragma unroll
  for (int kk = 0; kk < K; kk += 32) {
    const int ko = kk + quad * 8;
    half8 a[4], b[NT];
#pragma unroll
    for (int rt = 0; rt < 4; ++rt) {
      int row = rowbase + rt * 16 + m15;
      row = row < M ? row : M - 1;
      if (A_F16) a[rt] = *(const half8*)((const _Float16*)Av + (size_t)row * K + ko);
      else       a[rt] = cvt_f32x8((const float*)Av + (size_t)row * K + ko);
    }
#pragma unroll
    for (int t = 0; t < NT; ++t)
      b[t] = *(const half8*)(W + (size_t)(colbase + t * 16 + m15) * K + ko);
#pragma unroll
    for (int t = 0; t < NT; ++t)
#pragma unroll
      for (int rt = 0; rt < 4; ++rt)
        acc[rt][t] = __builtin_amdgcn_mfma_f32_16x16x32_f16(a[rt], b[t], acc[rt][t], 0, 0, 0);
  }

#pragma unroll
  for (int rt = 0; rt < 4; ++rt) {
    const int orow = rowbase + rt * 16 + quad * 4;
#pragma unroll
    for (int t = 0; t < NT; ++t) {
      const int col = colbase + t * 16 + m15;
      const float bv = bias[col];
#pragma unroll
      for (int i = 0; i < 4; ++i) {
        const int r = orow + i;
        if (r < M) {
          const float v = acc[rt][t][i] + bv;
          if (OUT_MODE == 0) ((float*)Cv)[(size_t)r * N + col] = v;
          else               ((_Float16*)Cv)[(size_t)r * N + col] = (_Float16)v;
        }
      }
    }
  }
}

// Sampler v3: 32 threads/query (8 channels each), 8 queries per 256-thread block.
// Thread: ql=t>>5, s=t&31, head h=s>>2, quad=s&3 -> channels h*32+quad*8.
// Per point: 4 clamped taps, validity folded into weights, 4 x 16B loads
// issued back-to-back (one stall per point), acc[8] in f32.  Low VGPR by
// construction (acc 8 + 16 load regs) -> no spills, high occupancy.
// Per-cam exec-masked skip keeps invisible-camera bytes off the bus.
__global__ __launch_bounds__(256, 4) void sampler(
    const _Float16* __restrict__ vp,     // (6, 5800, 256) f16
    const _Float16* __restrict__ qproj,  // (LQ, 192) f16: [0,128)=off, [128,192)=attn
    const float* __restrict__ ref,       // f32 (6, 1, LQ, 4, 2)
    const int* __restrict__ bev,         // int32 (6, 1, LQ, 4)
    _Float16* __restrict__ slots)        // (LQ, 256) f16
{
  const int t    = threadIdx.x;
  const int ql   = t >> 5;
  const int s    = t & 31;
  const int h    = s >> 2;
  const int quad = s & 3;
  const int q    = blockIdx.x * 8 + ql;
  const bool qok = q < LQ;

  __shared__ float s_off[8][128];
  __shared__ float s_aw[8][64];
  __shared__ float s_ref[8][48];
  __shared__ int   s_vis[8][6];

  if (s < 6) s_vis[ql][s] = 0;
  if (qok) {
    const _Float16* qp = qproj + (size_t)q * 192;
#pragma unroll
    for (int rep = 0; rep < 6; ++rep) {
      const int j = s + rep * 32;
      const float v = (float)qp[j];
      if (j < 128) s_off[ql][j] = v * ((j & 1) ? (1.f / 58.f) : (1.f / 100.f));
      else         s_aw[ql][j - 128] = v;
    }
#pragma unroll
    for (int rep = 0; rep < 2; ++rep) {
      const int k = s + rep * 32;
      if (k < 48) s_ref[ql][k] = ref[((size_t)(k >> 3) * LQ + q) * 8 + (k & 7)];
    }
    if (s < 6) {
      const int* bm = bev + ((size_t)s * LQ + q) * 4;
      s_vis[ql][s] = (bm[0] + bm[1] + bm[2] + bm[3]) > 0 ? 1 : 0;
    }
  }
  __syncthreads();

  // per-head softmax (redundant across the 4 lanes of a head)
  float w8[8];
  {
    float m = -1e30f;
#pragma unroll
    for (int p = 0; p < 8; ++p) m = fmaxf(m, s_aw[ql][h * 8 + p]);
    float ssum = 0.f;
#pragma unroll
    for (int p = 0; p < 8; ++p) { w8[p] = __expf(s_aw[ql][h * 8 + p] - m); ssum += w8[p]; }
    const float inv = 1.f / ssum;
#pragma unroll
    for (int p = 0; p < 8; ++p) w8[p] *= inv;
  }

  int cnt = 0;
#pragma unroll
  for (int c = 0; c < 6; ++c) cnt += s_vis[ql][c];
  const float invc = 1.f / (float)(cnt > 0 ? cnt : 1);

  float acc[8];
#pragma unroll
  for (int i = 0; i < 8; ++i) acc[i] = 0.f;

  const int chbase = h * 32 + quad * 8;

  for (int cam = 0; cam < NCAMS; ++cam) {
    if (!s_vis[ql][cam]) continue;   // exec-masked: invisible query lanes issue no loads
    const _Float16* vpc = vp + (size_t)cam * (S_TOT * CDIM) + chbase;
#pragma unroll 2
    for (int p = 0; p < 8; ++p) {
      const int z = p & 3;
      const float x = (s_ref[ql][cam * 8 + z * 2 + 0] + s_off[ql][(h * 8 + p) * 2 + 0]) * 100.f - 0.5f;
      const float y = (s_ref[ql][cam * 8 + z * 2 + 1] + s_off[ql][(h * 8 + p) * 2 + 1]) * 58.f - 0.5f;
      const float x0f = floorf(x), y0f = floorf(y);
      const float fx = x - x0f, fy = y - y0f;
      const int x0 = (int)x0f, y0 = (int)y0f;
      const int x1 = x0 + 1,  y1 = y0 + 1;
      const float wgt = w8[p];
      const float gx0 = 1.f - fx, gx1 = fx;
      const float gy0 = (1.f - fy) * wgt, gy1 = fy * wgt;
      // validity folded into weights; addresses clamped in-bounds
      const float vx0 = ((unsigned)x0 < SPA_W) ? 1.f : 0.f;
      const float vx1 = ((unsigned)x1 < SPA_W) ? 1.f : 0.f;
      const float vy0 = ((unsigned)y0 < SPA_H) ? 1.f : 0.f;
      const float vy1 = ((unsigned)y1 < SPA_H) ? 1.f : 0.f;
      const float w00 = gy0 * gx0 * (vy0 * vx0);
      const float w01 = gy0 * gx1 * (vy0 * vx1);
      const float w10 = gy1 * gx0 * (vy1 * vx0);
      const float w11 = gy1 * gx1 * (vy1 * vx1);
      const int x0c = min(max(x0, 0), SPA_W - 1);
      const int x1c = min(max(x1, 0), SPA_W - 1);
      const int y0c = min(max(y0, 0), SPA_H - 1);
      const int y1c = min(max(y1, 0), SPA_H - 1);
      const int r0 = y0c * SPA_W, r1 = y1c * SPA_W;
      const _Float16* p00 = vpc + ((size_t)(r0 + x0c) << 8);
      const _Float16* p01 = vpc + ((size_t)(r0 + x1c) << 8);
      const _Float16* p10 = vpc + ((size_t)(r1 + x0c) << 8);
      const _Float16* p11 = vpc + ((size_t)(r1 + x1c) << 8);
      // 4 x 16B loads in flight, then consume
      half8 a00 = *(const half8*)p00;
      half8 a01 = *(const half8*)p01;
      half8 a10 = *(const half8*)p10;
      half8 a11 = *(const half8*)p11;
#pragma unroll
      for (int i = 0; i < 8; ++i) {
        float v = acc[i];
        v = fmaf(w00, (float)a00[i], v);
        v = fmaf(w01, (float)a01[i], v);
        v = fmaf(w10, (float)a10[i], v);
        v = fmaf(w11, (float)a11[i], v);
        acc[i] = v;
      }
    }
  }

  if (qok) {
    half8 o;
#pragma unroll
    for (int i = 0; i < 8; ++i) o[i] = (_Float16)(acc[i] * invc);
    *(half8*)(slots + (size_t)q * CDIM + chbase) = o;
  }
}

extern "C" void kernel_launch(void* const* d_in, const int* in_sizes, int n_in,
                              void* d_out, int out_size, void* d_ws, size_t ws_size,
                              hipStream_t stream) {
  const float* query  = (const float*)d_in[0];
  const float* refpts = (const float*)d_in[1];
  const int*   bev    = (const int*)d_in[2];
  const float* value  = (const float*)d_in[3];
  const float* W_off  = (const float*)d_in[4];
  const float* b_off  = (const float*)d_in[5];
  const float* W_attn = (const float*)d_in[6];
  const float* b_attn = (const float*)d_in[7];
  const float* W_val  = (const float*)d_in[8];
  const float* b_val  = (const float*)d_in[9];
  const float* W_out  = (const float*)d_in[10];
  const float* b_out  = (const float*)d_in[11];

  char* ws = (char*)d_ws;
  _Float16* Wv_h    = (_Float16*)(ws + 0);        // 65536 f16
  _Float16* Wo_h    = (_Float16*)(ws + 131072);   // 65536 f16
  _Float16* Wcat_h  = (_Float16*)(ws + 262144);   // 49152 f16 (end 360448)
  float*    biascat = (float*)   (ws + 360448);   // 192 f32 (end 361216)
  _Float16* vp      = (_Float16*)(ws + 361216);   // 34800*256 f16 = 17,817,600
  _Float16* qproj   = (_Float16*)(ws + 18178816); // 22500*192 f16 =  8,640,000
  _Float16* slots   = (_Float16*)(ws + 26818816); // 22500*256 f16 = 11,520,000
                                                  // total: 38,338,816 B

  cvt_weights_all<<<704, 256, 0, stream>>>(W_val, W_out, W_off, W_attn,
                                           b_off, b_attn, Wv_h, biascat);

  // value projection: 34800 x 256
  gemm64<256, false, 2><<<(34800 + 63) / 64, 256, 0, stream>>>(value, Wv_h, b_val, vp, 34800);
  // fused query projection: 22500 x 192 (off ++ attn)
  gemm64<192, false, 2><<<(LQ + 63) / 64, 256, 0, stream>>>(query, Wcat_h, biascat, qproj, LQ);

  sampler<<<(LQ + 7) / 8, 256, 0, stream>>>(vp, qproj, refpts, bev, slots);

  // output projection: f16 slots -> f32 d_out
  gemm64<256, true, 0><<<(LQ + 63) / 64, 256, 0, stream>>>(slots, Wo_h, b_out, d_out, LQ);
}

// Round 3
// 381.019 us; speedup vs baseline: 1.5147x; 1.2511x over previous
//
#include <hip/hip_runtime.h>

#define LQ     22500
#define SPA_H  58
#define SPA_W  100
#define S_TOT  5800
#define NCAMS  6
#define CDIM   256
#define NB_VAL 544   // ceil(34800/64)
#define NB_Q   352   // ceil(22500/64)
#define NB_VIS 88    // ceil(22500/256)

typedef __attribute__((ext_vector_type(8))) _Float16 half8;
typedef __attribute__((ext_vector_type(4))) float f32x4;

__device__ __forceinline__ half8 cvt_f32x8(const float* p) {
  f32x4 a = *(const f32x4*)p;
  f32x4 b = *(const f32x4*)(p + 4);
  half8 r;
  r[0] = (_Float16)a.x; r[1] = (_Float16)a.y; r[2] = (_Float16)a.z; r[3] = (_Float16)a.w;
  r[4] = (_Float16)b.x; r[5] = (_Float16)b.y; r[6] = (_Float16)b.z; r[7] = (_Float16)b.w;
  return r;
}

// C[M x N] = A[M x 256] @ W[N x 256]^T + bias.  64-row M-tile, 4 waves own
// disjoint column ranges.  A f32 (inline cvt), W f32 (inline cvt -> same
// numerics as the old cvt kernel).  BSEL=1: W/bias split at col 128
// (W_off ++ W_attn).  OUT_MODE: 0=f32, 2=f16.
template<int N, int OUT_MODE, int BSEL>
__device__ __forceinline__ void gemm_body(
    const float* __restrict__ A, const float* __restrict__ W0,
    const float* __restrict__ W1, const float* __restrict__ b0,
    const float* __restrict__ b1, void* __restrict__ Cv, int M, int bid) {
  constexpr int K  = CDIM;
  constexpr int NT = (N / 4) / 16;
  const int lane = threadIdx.x & 63;
  const int wave = threadIdx.x >> 6;
  const int m15  = lane & 15;
  const int quad = lane >> 4;
  const int rowbase = bid * 64;
  const int colbase = wave * (N / 4);

  // per-lane W row pointers + bias, hoisted out of the K-loop
  const float* wp[NT];
  float bv[NT];
#pragma unroll
  for (int t = 0; t < NT; ++t) {
    const int c = colbase + t * 16 + m15;
    if (BSEL == 0) { wp[t] = W0 + (size_t)c * K; bv[t] = b0[c]; }
    else {
      wp[t] = (c < 128) ? (W0 + (size_t)c * K) : (W1 + (size_t)(c - 128) * K);
      bv[t] = (c < 128) ? b0[c] : b1[c - 128];
    }
  }

  f32x4 acc[4][NT];
#pragma unroll
  for (int rt = 0; rt < 4; ++rt)
#pragma unroll
    for (int t = 0; t < NT; ++t) acc[rt][t] = (f32x4){0.f, 0.f, 0.f, 0.f};

#pragma unroll
  for (int kk = 0; kk < K; kk += 32) {
    const int ko = kk + quad * 8;
    half8 a[4], b[NT];
#pragma unroll
    for (int rt = 0; rt < 4; ++rt) {
      int row = rowbase + rt * 16 + m15;
      row = row < M ? row : M - 1;
      a[rt] = cvt_f32x8(A + (size_t)row * K + ko);
    }
#pragma unroll
    for (int t = 0; t < NT; ++t) b[t] = cvt_f32x8(wp[t] + ko);
#pragma unroll
    for (int t = 0; t < NT; ++t)
#pragma unroll
      for (int rt = 0; rt < 4; ++rt)
        acc[rt][t] = __builtin_amdgcn_mfma_f32_16x16x32_f16(a[rt], b[t], acc[rt][t], 0, 0, 0);
  }

#pragma unroll
  for (int rt = 0; rt < 4; ++rt) {
    const int orow = rowbase + rt * 16 + quad * 4;
#pragma unroll
    for (int t = 0; t < NT; ++t) {
      const int col = colbase + t * 16 + m15;
#pragma unroll
      for (int i = 0; i < 4; ++i) {
        const int r = orow + i;
        if (r < M) {
          const float v = acc[rt][t][i] + bv[t];
          if (OUT_MODE == 0) ((float*)Cv)[(size_t)r * N + col] = v;
          else               ((_Float16*)Cv)[(size_t)r * N + col] = (_Float16)v;
        }
      }
    }
  }
}

// per-query visibility mask + 1/count
__device__ __forceinline__ void vis_body(const int* __restrict__ bev,
                                         unsigned char* __restrict__ vm,
                                         float* __restrict__ invc, int idx) {
  if (idx >= LQ) return;
  int cnt = 0; unsigned m = 0;
#pragma unroll
  for (int c = 0; c < NCAMS; ++c) {
    const int4 b4 = *(const int4*)(bev + ((size_t)c * LQ + idx) * 4);
    const int v = (b4.x + b4.y + b4.z + b4.w) > 0 ? 1 : 0;
    m |= (unsigned)v << c; cnt += v;
  }
  vm[idx] = (unsigned char)m;
  invc[idx] = 1.f / (float)(cnt > 0 ? cnt : 1);
}

// Fused front-end: [0,544) value GEMM, [544,896) query GEMM (off++attn),
// [896,984) visibility precompute.  One launch -> 2x occupancy vs serial.
__global__ __launch_bounds__(256, 2) void fused_front(
    const float* __restrict__ value, const float* __restrict__ query,
    const int* __restrict__ bev,
    const float* __restrict__ W_val, const float* __restrict__ b_val,
    const float* __restrict__ W_off, const float* __restrict__ b_off,
    const float* __restrict__ W_attn, const float* __restrict__ b_attn,
    _Float16* __restrict__ vp, _Float16* __restrict__ qproj,
    unsigned char* __restrict__ vm, float* __restrict__ invc) {
  const int bid = blockIdx.x;
  if (bid < NB_VAL)
    gemm_body<256, 2, 0>(value, W_val, nullptr, b_val, nullptr, vp, NCAMS * S_TOT, bid);
  else if (bid < NB_VAL + NB_Q)
    gemm_body<192, 2, 1>(query, W_off, W_attn, b_off, b_attn, qproj, LQ, bid - NB_VAL);
  else
    vis_body(bev, vm, invc, (bid - NB_VAL - NB_Q) * 256 + (int)threadIdx.x);
}

__global__ __launch_bounds__(256, 2) void out_gemm(
    const float* __restrict__ slots, const float* __restrict__ W_out,
    const float* __restrict__ b_out, float* __restrict__ out) {
  gemm_body<256, 0, 0>(slots, W_out, nullptr, b_out, nullptr, out, LQ, blockIdx.x);
}

// One camera per launch: per-cam value slice (2.97 MB) is L2-resident on every
// XCD -> no thrash regardless of request rate.  Keeps v3's fast engine:
// 32 lanes/query, clamped 4-tap batch, 0 bank conflicts, low VGPR.
// PASS0 initializes f32 slots; later passes RMW-accumulate (stream-serialized).
template<int PASS0>
__global__ __launch_bounds__(256, 4) void sampler_pass(
    const _Float16* __restrict__ vp,     // (6, 5800, 256) f16
    const _Float16* __restrict__ qproj,  // (LQ, 192) f16
    const float* __restrict__ ref,       // f32 (6, 1, LQ, 4, 2)
    const unsigned char* __restrict__ vm,
    const float* __restrict__ invc,
    float* __restrict__ slots,           // (LQ, 256) f32 accumulator
    int cam)
{
  const int t    = threadIdx.x;
  const int ql   = t >> 5;
  const int s    = t & 31;
  const int h    = s >> 2;
  const int quad = s & 3;
  const int q    = blockIdx.x * 8 + ql;
  const bool qok = q < LQ;

  __shared__ float s_off[8][128];
  __shared__ float s_aw[8][64];
  __shared__ float s_ref[8][8];

  if (qok) {
    const _Float16* qp = qproj + (size_t)q * 192;
#pragma unroll
    for (int rep = 0; rep < 6; ++rep) {
      const int j = s + rep * 32;
      const float v = (float)qp[j];
      if (j < 128) s_off[ql][j] = v * ((j & 1) ? (1.f / 58.f) : (1.f / 100.f));
      else         s_aw[ql][j - 128] = v;
    }
    if (s < 8) s_ref[ql][s] = ref[((size_t)cam * LQ + q) * 8 + s];
  }
  __syncthreads();

  const bool vis = qok && ((vm[q] >> cam) & 1);
  float acc[8];
#pragma unroll
  for (int i = 0; i < 8; ++i) acc[i] = 0.f;

  if (vis) {
    // per-head softmax (redundant across the 4 lanes of a head)
    float w8[8];
    float m = -1e30f;
#pragma unroll
    for (int p = 0; p < 8; ++p) m = fmaxf(m, s_aw[ql][h * 8 + p]);
    float ssum = 0.f;
#pragma unroll
    for (int p = 0; p < 8; ++p) { w8[p] = __expf(s_aw[ql][h * 8 + p] - m); ssum += w8[p]; }
    const float inv = 1.f / ssum;
#pragma unroll
    for (int p = 0; p < 8; ++p) w8[p] *= inv;

    const _Float16* vpc = vp + (size_t)cam * (S_TOT * CDIM) + h * 32 + quad * 8;
#pragma unroll 2
    for (int p = 0; p < 8; ++p) {
      const int z = p & 3;
      const float x = (s_ref[ql][z * 2 + 0] + s_off[ql][(h * 8 + p) * 2 + 0]) * 100.f - 0.5f;
      const float y = (s_ref[ql][z * 2 + 1] + s_off[ql][(h * 8 + p) * 2 + 1]) * 58.f - 0.5f;
      const float x0f = floorf(x), y0f = floorf(y);
      const float fx = x - x0f, fy = y - y0f;
      const int x0 = (int)x0f, y0 = (int)y0f;
      const int x1 = x0 + 1,  y1 = y0 + 1;
      const float wgt = w8[p];
      const float gx0 = 1.f - fx, gx1 = fx;
      const float gy0 = (1.f - fy) * wgt, gy1 = fy * wgt;
      const float vx0 = ((unsigned)x0 < SPA_W) ? 1.f : 0.f;
      const float vx1 = ((unsigned)x1 < SPA_W) ? 1.f : 0.f;
      const float vy0 = ((unsigned)y0 < SPA_H) ? 1.f : 0.f;
      const float vy1 = ((unsigned)y1 < SPA_H) ? 1.f : 0.f;
      const float w00 = gy0 * gx0 * (vy0 * vx0);
      const float w01 = gy0 * gx1 * (vy0 * vx1);
      const float w10 = gy1 * gx0 * (vy1 * vx0);
      const float w11 = gy1 * gx1 * (vy1 * vx1);
      const int x0c = min(max(x0, 0), SPA_W - 1);
      const int x1c = min(max(x1, 0), SPA_W - 1);
      const int y0c = min(max(y0, 0), SPA_H - 1);
      const int y1c = min(max(y1, 0), SPA_H - 1);
      const int r0 = y0c * SPA_W, r1 = y1c * SPA_W;
      const _Float16* p00 = vpc + ((size_t)(r0 + x0c) << 8);
      const _Float16* p01 = vpc + ((size_t)(r0 + x1c) << 8);
      const _Float16* p10 = vpc + ((size_t)(r1 + x0c) << 8);
      const _Float16* p11 = vpc + ((size_t)(r1 + x1c) << 8);
      half8 a00 = *(const half8*)p00;
      half8 a01 = *(const half8*)p01;
      half8 a10 = *(const half8*)p10;
      half8 a11 = *(const half8*)p11;
#pragma unroll
      for (int i = 0; i < 8; ++i) {
        float v = acc[i];
        v = fmaf(w00, (float)a00[i], v);
        v = fmaf(w01, (float)a01[i], v);
        v = fmaf(w10, (float)a10[i], v);
        v = fmaf(w11, (float)a11[i], v);
        acc[i] = v;
      }
    }
  }

  if (qok) {
    const float sc = invc[q];
    float* sp = slots + (size_t)q * CDIM + h * 32 + quad * 8;
    if (PASS0) {
      f32x4 o0, o1;
#pragma unroll
      for (int i = 0; i < 4; ++i) { o0[i] = acc[i] * sc; o1[i] = acc[4 + i] * sc; }
      *(f32x4*)sp = o0;
      *(f32x4*)(sp + 4) = o1;
    } else if (vis) {
      f32x4 o0 = *(const f32x4*)sp;
      f32x4 o1 = *(const f32x4*)(sp + 4);
#pragma unroll
      for (int i = 0; i < 4; ++i) { o0[i] += acc[i] * sc; o1[i] += acc[4 + i] * sc; }
      *(f32x4*)sp = o0;
      *(f32x4*)(sp + 4) = o1;
    }
  }
}

extern "C" void kernel_launch(void* const* d_in, const int* in_sizes, int n_in,
                              void* d_out, int out_size, void* d_ws, size_t ws_size,
                              hipStream_t stream) {
  const float* query  = (const float*)d_in[0];
  const float* refpts = (const float*)d_in[1];
  const int*   bev    = (const int*)d_in[2];
  const float* value  = (const float*)d_in[3];
  const float* W_off  = (const float*)d_in[4];
  const float* b_off  = (const float*)d_in[5];
  const float* W_attn = (const float*)d_in[6];
  const float* b_attn = (const float*)d_in[7];
  const float* W_val  = (const float*)d_in[8];
  const float* b_val  = (const float*)d_in[9];
  const float* W_out  = (const float*)d_in[10];
  const float* b_out  = (const float*)d_in[11];

  char* ws = (char*)d_ws;
  _Float16*      vp    = (_Float16*)(ws + 0);          // 34800*256 f16 = 17,817,600
  _Float16*      qproj = (_Float16*)(ws + 17817600);   // 22500*192 f16 =  8,640,000
  float*         slots = (float*)   (ws + 26457600);   // 22500*256 f32 = 23,040,000
  unsigned char* vm    = (unsigned char*)(ws + 49497600); // 22500 (pad 22,528)
  float*         invc  = (float*)   (ws + 49520128);   // 22500 f32 = 90,000
                                                       // total: ~49.6 MB

  fused_front<<<NB_VAL + NB_Q + NB_VIS, 256, 0, stream>>>(
      value, query, bev, W_val, b_val, W_off, b_off, W_attn, b_attn,
      vp, qproj, vm, invc);

  sampler_pass<1><<<(LQ + 7) / 8, 256, 0, stream>>>(vp, qproj, refpts, vm, invc, slots, 0);
  for (int cam = 1; cam < NCAMS; ++cam)
    sampler_pass<0><<<(LQ + 7) / 8, 256, 0, stream>>>(vp, qproj, refpts, vm, invc, slots, cam);

  out_gemm<<<NB_Q, 256, 0, stream>>>(slots, W_out, b_out, (float*)d_out);
}